// Round 14
// baseline (515.950 us; speedup 1.0000x reference)
//
#include <hip/hip_runtime.h>
#include <hip/hip_bf16.h>
#include <math.h>

#define N_NODES 100000
#define N_EDGES 3200000
#define NFEAT 512
#define NHID 256
#define NCLASS 40
#define LDP 40     // padded LDS row stride in bf16 elems
#define NB1 256    // coarse buckets
#define RPB1 391   // rows per bucket (256*391 = 100096 >= 100000)
#define NBLK 256   // scatter blocks
#define CHUNK 12500 // N_EDGES / NBLK exactly
#define SCAP 13312 // sortD LDS record cap
#define WTBLKS 512 // (NHID*NFEAT)/256

#if __has_builtin(__builtin_amdgcn_cvt_pk_fp8_f32) && __has_builtin(__builtin_amdgcn_cvt_pk_f32_fp8)
#define SUP_FP8 1
#else
#define SUP_FP8 0
#endif

typedef short bf16x8 __attribute__((ext_vector_type(8)));
typedef float f32x4 __attribute__((ext_vector_type(4)));
typedef float f32x2 __attribute__((ext_vector_type(2)));
typedef unsigned long long u64;

__device__ __forceinline__ unsigned short f2bf(float f) {
    unsigned int u = __builtin_bit_cast(unsigned int, f);
    u += 0x7fffu + ((u >> 16) & 1u);           // round-to-nearest-even
    return (unsigned short)(u >> 16);
}
__device__ __forceinline__ float bflo(unsigned int u) { return __builtin_bit_cast(float, u << 16); }
__device__ __forceinline__ float bfhi(unsigned int u) { return __builtin_bit_cast(float, u & 0xffff0000u); }
__device__ __forceinline__ unsigned int ecol_of(u64 ev) { return (unsigned int)(ev & 0xffffffffu); }
__device__ __forceinline__ float eval_of(u64 ev) { return __builtin_bit_cast(float, (unsigned int)(ev >> 32)); }

// ---------------- CSR pass A + weight transpose (merged) ----------------
__global__ __launch_bounds__(256) void k_histA_wt(const int* __restrict__ erow, int* __restrict__ hist,
                                                  const float* __restrict__ W1, const float* __restrict__ W2,
                                                  unsigned short* __restrict__ W1T, unsigned short* __restrict__ W2T) {
    __shared__ int lh[NB1];
    const int t = threadIdx.x, blk = blockIdx.x;
    if (blk < NBLK) {
        lh[t] = 0;
        __syncthreads();
        const int base = blk * CHUNK;
        for (int i = t; i < CHUNK; i += 256)
            atomicAdd(&lh[erow[base + i] / RPB1], 1);
        __syncthreads();
        hist[blk * NB1 + t] = lh[t];
    } else {
        int i = (blk - NBLK) * 256 + t;   // 0 .. NHID*NFEAT-1
        int nn = i >> 9, k = i & 511;
        W1T[i] = f2bf(W1[k * NHID + nn]);
        if (i < 64 * NHID) {
            int n2 = i >> 8, k2 = i & 255;
            W2T[i] = (n2 < NCLASS) ? f2bf(W2[k2 * NCLASS + n2]) : (unsigned short)0;
        }
    }
}

__global__ __launch_bounds__(256) void k_scanB(const int* __restrict__ hist,
                                               int* __restrict__ offs, int* __restrict__ bucketptr) {
    __shared__ int sd[256];
    const int b = threadIdx.x;
    int run = 0;
#pragma unroll 8
    for (int blk = 0; blk < NBLK; ++blk) {
        int v = hist[blk * NB1 + b];
        offs[blk * NB1 + b] = run;
        run += v;
    }
    sd[b] = run;
    __syncthreads();
    for (int off = 1; off < 256; off <<= 1) {
        int x = (b >= off) ? sd[b - off] : 0;
        __syncthreads();
        sd[b] += x;
        __syncthreads();
    }
    bucketptr[b] = sd[b] - run;
    if (b == 255) bucketptr[NB1] = sd[255];
}

// Pass C: in-LDS counting sort (hist reused), linear nt write-out
__global__ __launch_bounds__(256) void k_scatC(const int* __restrict__ erow, const int* __restrict__ ecol,
                                               const float* __restrict__ eval_,
                                               const int* __restrict__ hist,
                                               const int* __restrict__ offs, const int* __restrict__ bucketptr,
                                               u64* __restrict__ tmp) {
    __shared__ u64 srec[CHUNK];            // 100 KB
    __shared__ unsigned char sbkt[CHUNK];  // 12.5 KB
    __shared__ int lscan[NB1];
    __shared__ int lcur[NB1];
    __shared__ int lsegbase[NB1];
    __shared__ int sd[256];
    const int t = threadIdx.x, blk = blockIdx.x;
    const int base = blk * CHUNK;
    lsegbase[t] = bucketptr[t] + offs[blk * NB1 + t];
    int v = hist[blk * NB1 + t];
    sd[t] = v;
    __syncthreads();
    for (int off = 1; off < 256; off <<= 1) {
        int x = (t >= off) ? sd[t - off] : 0;
        __syncthreads();
        sd[t] += x;
        __syncthreads();
    }
    lscan[t] = sd[t] - v;
    lcur[t] = sd[t] - v;
    __syncthreads();
    for (int i = t; i < CHUNK; i += 256) {
        int r = erow[base + i];
        int c = ecol[base + i];
        unsigned int vb = __builtin_bit_cast(unsigned int, eval_[base + i]);
        int b = r / RPB1;
        int rl = r - b * RPB1;
        int pos = atomicAdd(&lcur[b], 1);
        srec[pos] = (u64)((unsigned int)c | ((unsigned int)rl << 17)) | ((u64)vb << 32);
        sbkt[pos] = (unsigned char)b;
    }
    __syncthreads();
    for (int i = t; i < CHUNK; i += 256) {
        int b = sbkt[i];
        __builtin_nontemporal_store(srec[i], &tmp[lsegbase[b] + (i - lscan[b])]);
    }
}

// Pass D: per-bucket fine sort; records cached in LDS (single nt read of tmp)
__global__ __launch_bounds__(512) void k_sortD(const int* __restrict__ bucketptr, const u64* __restrict__ tmp,
                                               u64* __restrict__ pedge, int* __restrict__ rowptr) {
    __shared__ u64 srec[SCAP];             // 106.5 KB
    __shared__ int lcnt[512];
    __shared__ int sc[512];
    __shared__ int lcur[512];
    const int b = blockIdx.x, t = threadIdx.x;
    const int beg = bucketptr[b], end = bucketptr[b + 1];
    const int n = end - beg;
    lcnt[t] = 0;
    __syncthreads();
    for (int i = t; i < n; i += 512) {
        u64 rec = __builtin_nontemporal_load(&tmp[beg + i]);
        if (i < SCAP) srec[i] = rec;
        atomicAdd(&lcnt[(int)((rec >> 17) & 0x1ff)], 1);
    }
    __syncthreads();
    sc[t] = lcnt[t];
    __syncthreads();
    for (int off = 1; off < 512; off <<= 1) {
        int x = (t >= off) ? sc[t - off] : 0;
        __syncthreads();
        sc[t] += x;
        __syncthreads();
    }
    int excl = sc[t] - lcnt[t];
    lcur[t] = excl;
    if (t < RPB1) {
        int row = b * RPB1 + t;
        if (row < N_NODES) rowptr[row] = beg + excl;
    }
    if (b == NB1 - 1 && t == 0) rowptr[N_NODES] = N_EDGES;
    __syncthreads();
    for (int i = t; i < n; i += 512) {
        u64 rec = (i < SCAP) ? srec[i] : __builtin_nontemporal_load(&tmp[beg + i]);
        int rl = (int)((rec >> 17) & 0x1ff);
        int pos = atomicAdd(&lcur[rl], 1);
        pedge[beg + pos] = rec & 0xFFFFFFFF0001FFFFull;
    }
}

// ---------------- GEMM1: support[row][256] = bf16(x) @ bf16(W1), stored fp8 ----------------
// register prefetch + LDS double-buffer, ONE barrier per K-step
__global__ __launch_bounds__(512) void k_gemm1(const float* __restrict__ X,
                                               const unsigned short* __restrict__ W1T,
                                               unsigned char* __restrict__ support8) {
    __shared__ unsigned short As[2][128 * LDP];
    __shared__ unsigned short Bs[2][256 * LDP];
    const int t = threadIdx.x;
    const int lane = t & 63;
    const int w = t >> 6;
    const int wm = w >> 2, wn = w & 3;
    const int l15 = lane & 15, l4 = lane >> 4;
    const int bm = blockIdx.x;

    f32x4 acc[4][4];
#pragma unroll
    for (int m = 0; m < 4; ++m)
#pragma unroll
        for (int n = 0; n < 4; ++n) acc[m][n] = (f32x4){0.f, 0.f, 0.f, 0.f};

    const int arow = t >> 2, aq = t & 3;
    const long growA = (long)bm * 128 + arow;
    const bool avalid = growA < N_NODES;
    const float* xsrc = X + growA * NFEAT + aq * 8;
    const int brow = t >> 1, bhalf = t & 1;
    const unsigned short* bsrc = W1T + (long)brow * NFEAT + bhalf * 16;
    const int adoff = arow * LDP + aq * 8;
    const int bdoff = brow * LDP + bhalf * 16;

    float4 a0r, a1r;
    uint4 b0r, b1r;
    if (avalid) {
        a0r = *(const float4*)(xsrc + 0);
        a1r = *(const float4*)(xsrc + 4);
    } else {
        a0r = make_float4(0.f, 0.f, 0.f, 0.f);
        a1r = make_float4(0.f, 0.f, 0.f, 0.f);
    }
    b0r = *(const uint4*)(bsrc + 0);
    b1r = *(const uint4*)(bsrc + 8);
    {
        union { uint4 q; unsigned short us[8]; } u;
        const float* af = (const float*)&a0r;
#pragma unroll
        for (int j = 0; j < 4; ++j) u.us[j] = f2bf(af[j]);
        const float* af1 = (const float*)&a1r;
#pragma unroll
        for (int j = 0; j < 4; ++j) u.us[4 + j] = f2bf(af1[j]);
        *(uint4*)&As[0][adoff] = u.q;
        *(uint4*)&Bs[0][bdoff] = b0r;
        *(uint4*)&Bs[0][bdoff + 8] = b1r;
    }
    __syncthreads();

    for (int ki = 0; ki < 16; ++ki) {
        const int cur = ki & 1;
        if (ki < 15) {
            int kt = (ki + 1) * 32;
            if (avalid) {
                a0r = *(const float4*)(xsrc + kt);
                a1r = *(const float4*)(xsrc + kt + 4);
            }
            b0r = *(const uint4*)(bsrc + kt);
            b1r = *(const uint4*)(bsrc + kt + 8);
        }

        bf16x8 afr[4], bfr[4];
#pragma unroll
        for (int m = 0; m < 4; ++m)
            afr[m] = *(const bf16x8*)&As[cur][(wm * 64 + m * 16 + l15) * LDP + l4 * 8];
#pragma unroll
        for (int n = 0; n < 4; ++n)
            bfr[n] = *(const bf16x8*)&Bs[cur][(wn * 64 + n * 16 + l15) * LDP + l4 * 8];
#pragma unroll
        for (int m = 0; m < 4; ++m)
#pragma unroll
            for (int n = 0; n < 4; ++n)
                acc[m][n] = __builtin_amdgcn_mfma_f32_16x16x32_bf16(bfr[n], afr[m], acc[m][n], 0, 0, 0);

        if (ki < 15) {
            union { uint4 q; unsigned short us[8]; } u;
            const float* af = (const float*)&a0r;
#pragma unroll
            for (int j = 0; j < 4; ++j) u.us[j] = avalid ? f2bf(af[j]) : (unsigned short)0;
            const float* af1 = (const float*)&a1r;
#pragma unroll
            for (int j = 0; j < 4; ++j) u.us[4 + j] = avalid ? f2bf(af1[j]) : (unsigned short)0;
            *(uint4*)&As[cur ^ 1][adoff] = u.q;
            *(uint4*)&Bs[cur ^ 1][bdoff] = b0r;
            *(uint4*)&Bs[cur ^ 1][bdoff + 8] = b1r;
        }
        __syncthreads();
    }

#pragma unroll
    for (int m = 0; m < 4; ++m) {
        long row = (long)bm * 128 + wm * 64 + m * 16 + l15;
        if (row < N_NODES) {
#pragma unroll
            for (int n = 0; n < 4; ++n) {
                int colb = wn * 64 + n * 16 + l4 * 4;
#if SUP_FP8
                int wv = 0;
                wv = __builtin_amdgcn_cvt_pk_fp8_f32(acc[m][n][0], acc[m][n][1], wv, false);
                wv = __builtin_amdgcn_cvt_pk_fp8_f32(acc[m][n][2], acc[m][n][3], wv, true);
                *(unsigned int*)&support8[(size_t)row * NHID + colb] = (unsigned int)wv;
#else
                ushort4 o;
                o.x = f2bf(acc[m][n][0]);
                o.y = f2bf(acc[m][n][1]);
                o.z = f2bf(acc[m][n][2]);
                o.w = f2bf(acc[m][n][3]);
                *(ushort4*)&support8[(size_t)row * NHID * 2 + colb * 2] = o;
#endif
            }
        }
    }
}

// ---------------- SpMM1 + bias + ReLU -> h (bf16). 2-pass column-sliced ----------------
// grid (25000, 2): y = column half. Pass gathers 128 B/edge (one cache line);
// hot slice 12.8 MB -> better per-XCD L2 residency. lane handles 2 fp8 cols.
__global__ __launch_bounds__(256) void k_spmm1(const int* __restrict__ rowptr,
                                               const u64* __restrict__ pedge,
                                               const unsigned char* __restrict__ support8,
                                               const float* __restrict__ b1,
                                               unsigned short* __restrict__ h) {
    int wrow = (blockIdx.x * 256 + threadIdx.x) >> 6;
    int lane = threadIdx.x & 63;
    if (wrow >= N_NODES) return;
    const int cb = blockIdx.y * 128 + lane * 2;    // this lane's 2 columns
    int beg = rowptr[wrow], end = rowptr[wrow + 1];
    float a0 = 0.f, a1 = 0.f;
    int e = beg;
#if SUP_FP8
    for (; e + 8 <= end; e += 8) {
        u64 ev[8];
#pragma unroll
        for (int j = 0; j < 8; ++j) ev[j] = __builtin_nontemporal_load(&pedge[e + j]);
        unsigned short g[8];
#pragma unroll
        for (int j = 0; j < 8; ++j)
            g[j] = *(const unsigned short*)&support8[(size_t)ecol_of(ev[j]) * NHID + cb];
#pragma unroll
        for (int j = 0; j < 8; ++j) {
            float v = eval_of(ev[j]);
            f32x2 p = __builtin_amdgcn_cvt_pk_f32_fp8((unsigned int)g[j], false);
            a0 = fmaf(v, p[0], a0);
            a1 = fmaf(v, p[1], a1);
        }
    }
    for (; e < end; ++e) {
        u64 ev = __builtin_nontemporal_load(&pedge[e]);
        float v = eval_of(ev);
        unsigned short g = *(const unsigned short*)&support8[(size_t)ecol_of(ev) * NHID + cb];
        f32x2 p = __builtin_amdgcn_cvt_pk_f32_fp8((unsigned int)g, false);
        a0 = fmaf(v, p[0], a0);
        a1 = fmaf(v, p[1], a1);
    }
#else
    for (; e + 8 <= end; e += 8) {
        u64 ev[8];
#pragma unroll
        for (int j = 0; j < 8; ++j) ev[j] = __builtin_nontemporal_load(&pedge[e + j]);
        unsigned int g[8];
#pragma unroll
        for (int j = 0; j < 8; ++j)
            g[j] = *(const unsigned int*)&support8[((size_t)ecol_of(ev[j]) * NHID + cb) * 2];
#pragma unroll
        for (int j = 0; j < 8; ++j) {
            float v = eval_of(ev[j]);
            a0 = fmaf(v, bflo(g[j]), a0);
            a1 = fmaf(v, bfhi(g[j]), a1);
        }
    }
    for (; e < end; ++e) {
        u64 ev = __builtin_nontemporal_load(&pedge[e]);
        float v = eval_of(ev);
        unsigned int g = *(const unsigned int*)&support8[((size_t)ecol_of(ev) * NHID + cb) * 2];
        a0 = fmaf(v, bflo(g), a0);
        a1 = fmaf(v, bfhi(g), a1);
    }
#endif
    float2 bb = *(const float2*)&b1[cb];
    a0 = fmaxf(a0 + bb.x, 0.f);
    a1 = fmaxf(a1 + bb.y, 0.f);
    unsigned int packed = (unsigned int)f2bf(a0) | ((unsigned int)f2bf(a1) << 16);
    *(unsigned int*)&h[(size_t)wrow * NHID + cb] = packed;
}

// ---------------- GEMM2: logits8[row][40] (fp8, 4 MB table -> L2-resident) = h @ W2 ----------------
__global__ __launch_bounds__(256) void k_gemm2(const unsigned short* __restrict__ H,
                                               const unsigned short* __restrict__ W2T,
                                               unsigned char* __restrict__ logits8) {
    __shared__ unsigned short As[128 * LDP];
    __shared__ unsigned short Bs[64 * LDP];
    const int t = threadIdx.x;
    const int lane = t & 63;
    const int w = t >> 6;
    const int wm = w >> 1, wn = w & 1;
    const int l15 = lane & 15, l4 = lane >> 4;
    const int bm = blockIdx.x;

    f32x4 acc[4][2];
#pragma unroll
    for (int m = 0; m < 4; ++m)
#pragma unroll
        for (int n = 0; n < 2; ++n) acc[m][n] = (f32x4){0.f, 0.f, 0.f, 0.f};

    const int srow = t >> 1, shalf = t & 1;
    const long grow = (long)bm * 128 + srow;
    const bool avalid = grow < N_NODES;
    const unsigned short* asrc = H + grow * NHID + shalf * 16;
    const int bn2 = t >> 2, bq = t & 3;
    const unsigned short* bsrc = W2T + bn2 * NHID + bq * 8;

    for (int kt = 0; kt < NHID; kt += 32) {
        uint4 a0, a1;
        if (avalid) {
            a0 = *(const uint4*)(asrc + kt);
            a1 = *(const uint4*)(asrc + kt + 8);
        } else {
            a0 = make_uint4(0, 0, 0, 0);
            a1 = make_uint4(0, 0, 0, 0);
        }
        uint4 bv = *(const uint4*)(bsrc + kt);
        *(uint4*)&As[srow * LDP + shalf * 16] = a0;
        *(uint4*)&As[srow * LDP + shalf * 16 + 8] = a1;
        *(uint4*)&Bs[bn2 * LDP + bq * 8] = bv;
        __syncthreads();

        bf16x8 afr[4], bfr[2];
#pragma unroll
        for (int m = 0; m < 4; ++m)
            afr[m] = *(const bf16x8*)&As[(wm * 64 + m * 16 + l15) * LDP + l4 * 8];
#pragma unroll
        for (int n = 0; n < 2; ++n)
            bfr[n] = *(const bf16x8*)&Bs[(wn * 32 + n * 16 + l15) * LDP + l4 * 8];
#pragma unroll
        for (int m = 0; m < 4; ++m)
#pragma unroll
            for (int n = 0; n < 2; ++n)
                acc[m][n] = __builtin_amdgcn_mfma_f32_16x16x32_bf16(bfr[n], afr[m], acc[m][n], 0, 0, 0);
        __syncthreads();
    }
#pragma unroll
    for (int m = 0; m < 4; ++m) {
        long row = (long)bm * 128 + wm * 64 + m * 16 + l15;
        if (row < N_NODES) {
#pragma unroll
            for (int n = 0; n < 2; ++n) {
                int colb = wn * 32 + n * 16 + l4 * 4;
                if (colb < NCLASS) {
#if SUP_FP8
                    int wv = 0;
                    wv = __builtin_amdgcn_cvt_pk_fp8_f32(acc[m][n][0], acc[m][n][1], wv, false);
                    wv = __builtin_amdgcn_cvt_pk_fp8_f32(acc[m][n][2], acc[m][n][3], wv, true);
                    *(unsigned int*)&logits8[(size_t)row * NCLASS + colb] = (unsigned int)wv;
#else
                    ushort4 o;
                    o.x = f2bf(acc[m][n][0]);
                    o.y = f2bf(acc[m][n][1]);
                    o.z = f2bf(acc[m][n][2]);
                    o.w = f2bf(acc[m][n][3]);
                    *(ushort4*)&logits8[((size_t)row * NCLASS + colb) * 2] = o;
#endif
                }
            }
        }
    }
}

// ---------------- SpMM2 + bias + log_softmax -> out (fp32) ----------------
// lane = eg*8+cl: 8 edge-groups x 8 col-lanes (cl<5 active, 8 fp8 cols each).
__global__ __launch_bounds__(256) void k_spmm2(const int* __restrict__ rowptr,
                                               const u64* __restrict__ pedge,
                                               const unsigned char* __restrict__ logits8,
                                               const float* __restrict__ b2, float* __restrict__ out) {
    int wrow = (blockIdx.x * 256 + threadIdx.x) >> 6;
    int lane = threadIdx.x & 63;
    if (wrow >= N_NODES) return;
    int beg = rowptr[wrow], end = rowptr[wrow + 1];
    const int eg = lane >> 3;      // 0..7 edge subgroup
    const int cl = lane & 7;       // 0..7, active if <5
    const bool colact = cl < 5;
    const int cb = colact ? cl * 8 : 0;   // column base (8 cols per lane)
    float acc[8];
#pragma unroll
    for (int j = 0; j < 8; ++j) acc[j] = 0.f;
#if SUP_FP8
    for (int e = beg + eg; e < end; e += 8) {
        u64 ev = __builtin_nontemporal_load(&pedge[e]);
        float v = eval_of(ev);
        uint2 g = *(const uint2*)&logits8[(size_t)ecol_of(ev) * NCLASS + cb];
        f32x2 p0 = __builtin_amdgcn_cvt_pk_f32_fp8(g.x, false);
        f32x2 p1 = __builtin_amdgcn_cvt_pk_f32_fp8(g.x, true);
        f32x2 p2 = __builtin_amdgcn_cvt_pk_f32_fp8(g.y, false);
        f32x2 p3 = __builtin_amdgcn_cvt_pk_f32_fp8(g.y, true);
        acc[0] = fmaf(v, p0[0], acc[0]); acc[1] = fmaf(v, p0[1], acc[1]);
        acc[2] = fmaf(v, p1[0], acc[2]); acc[3] = fmaf(v, p1[1], acc[3]);
        acc[4] = fmaf(v, p2[0], acc[4]); acc[5] = fmaf(v, p2[1], acc[5]);
        acc[6] = fmaf(v, p3[0], acc[6]); acc[7] = fmaf(v, p3[1], acc[7]);
    }
#else
    for (int e = beg + eg; e < end; e += 8) {
        u64 ev = __builtin_nontemporal_load(&pedge[e]);
        float v = eval_of(ev);
        uint4 g = *(const uint4*)&logits8[((size_t)ecol_of(ev) * NCLASS + cb) * 2];
        acc[0] = fmaf(v, bflo(g.x), acc[0]); acc[1] = fmaf(v, bfhi(g.x), acc[1]);
        acc[2] = fmaf(v, bflo(g.y), acc[2]); acc[3] = fmaf(v, bfhi(g.y), acc[3]);
        acc[4] = fmaf(v, bflo(g.z), acc[4]); acc[5] = fmaf(v, bfhi(g.z), acc[5]);
        acc[6] = fmaf(v, bflo(g.w), acc[6]); acc[7] = fmaf(v, bfhi(g.w), acc[7]);
    }
#endif
#pragma unroll
    for (int off = 8; off < 64; off <<= 1)
#pragma unroll
        for (int j = 0; j < 8; ++j)
            acc[j] += __shfl_xor(acc[j], off, 64);
    if (colact) {
        float4 bb0 = *(const float4*)&b2[cb];
        float4 bb1 = *(const float4*)&b2[cb + 4];
        acc[0] += bb0.x; acc[1] += bb0.y; acc[2] += bb0.z; acc[3] += bb0.w;
        acc[4] += bb1.x; acc[5] += bb1.y; acc[6] += bb1.z; acc[7] += bb1.w;
    }
    float mv = -INFINITY;
    if (colact) {
#pragma unroll
        for (int j = 0; j < 8; ++j) mv = fmaxf(mv, acc[j]);
    }
#pragma unroll
    for (int off = 1; off < 8; off <<= 1) mv = fmaxf(mv, __shfl_xor(mv, off, 64));
    float s = 0.f;
    if (colact) {
#pragma unroll
        for (int j = 0; j < 8; ++j) s += __expf(acc[j] - mv);
    }
#pragma unroll
    for (int off = 1; off < 8; off <<= 1) s += __shfl_xor(s, off, 64);
    if (colact && eg == 0) {
        float ls = __logf(s);
        float4 o0, o1;
        o0.x = acc[0] - mv - ls; o0.y = acc[1] - mv - ls;
        o0.z = acc[2] - mv - ls; o0.w = acc[3] - mv - ls;
        o1.x = acc[4] - mv - ls; o1.y = acc[5] - mv - ls;
        o1.z = acc[6] - mv - ls; o1.w = acc[7] - mv - ls;
        *(float4*)&out[(size_t)wrow * NCLASS + cb] = o0;
        *(float4*)&out[(size_t)wrow * NCLASS + cb + 4] = o1;
    }
}

extern "C" void kernel_launch(void* const* d_in, const int* in_sizes, int n_in,
                              void* d_out, int out_size, void* d_ws, size_t ws_size,
                              hipStream_t stream) {
    const float* x    = (const float*)d_in[0];
    const int*   erow = (const int*)d_in[1];
    const int*   ecol = (const int*)d_in[2];
    const float* eval_ = (const float*)d_in[3];
    const float* W1   = (const float*)d_in[4];
    const float* b1   = (const float*)d_in[5];
    const float* W2   = (const float*)d_in[6];
    const float* b2   = (const float*)d_in[7];
    float* out = (float*)d_out;

    char* p = (char*)d_ws;
    auto alloc = [&](size_t b) { char* r = p; p += (b + 255) & ~(size_t)255; return r; };
    int* hist              = (int*)alloc((size_t)NBLK * NB1 * 4);
    int* offs              = (int*)alloc((size_t)NBLK * NB1 * 4);
    int* bucketptr         = (int*)alloc((size_t)(NB1 + 1) * 4);
    int* rowptr            = (int*)alloc((size_t)(N_NODES + 1) * 4);
    u64* tmp               = (u64*)alloc((size_t)N_EDGES * 8);
    u64* pedge             = (u64*)alloc((size_t)N_EDGES * 8);
    unsigned short* W1T    = (unsigned short*)alloc((size_t)NHID * NFEAT * 2);
    unsigned short* W2T    = (unsigned short*)alloc((size_t)64 * NHID * 2);
    unsigned char* support8= (unsigned char*)alloc((size_t)N_NODES * NHID * 2); // 2B reserved (bf16 fallback)
    unsigned short* h      = (unsigned short*)alloc((size_t)N_NODES * NHID * 2);
    unsigned char* logits8 = (unsigned char*)alloc((size_t)N_NODES * NCLASS * 2); // 2B reserved (bf16 fallback)

    k_histA_wt<<<NBLK + WTBLKS, 256, 0, stream>>>(erow, hist, W1, W2, W1T, W2T);
    k_scanB<<<1, 256, 0, stream>>>(hist, offs, bucketptr);
    k_scatC<<<NBLK, 256, 0, stream>>>(erow, ecol, eval_, hist, offs, bucketptr, tmp);
    k_sortD<<<NB1, 512, 0, stream>>>(bucketptr, tmp, pedge, rowptr);
    k_gemm1<<<(N_NODES + 127) / 128, 512, 0, stream>>>(x, W1T, support8);
    k_spmm1<<<dim3((N_NODES + 3) / 4, 2), 256, 0, stream>>>(rowptr, pedge, support8, b1, h);
    k_gemm2<<<(N_NODES + 127) / 128, 256, 0, stream>>>(h, W2T, logits8);
    k_spmm2<<<(N_NODES + 3) / 4, 256, 0, stream>>>(rowptr, pedge, logits8, b2, out);
}

// Round 15
// 412.214 us; speedup vs baseline: 1.2517x; 1.2517x over previous
//
#include <hip/hip_runtime.h>
#include <hip/hip_bf16.h>
#include <math.h>

#define N_NODES 100000
#define N_EDGES 3200000
#define NFEAT 512
#define NHID 256
#define NCLASS 40
#define LDP 40     // padded LDS row stride in bf16 elems
#define NB1 256    // coarse buckets
#define RPB1 391   // rows per bucket (256*391 = 100096 >= 100000)
#define NBLK 256   // scatter blocks
#define CHUNK 12500 // N_EDGES / NBLK exactly
#define SCAP 13312 // sortD LDS record cap
#define WTBLKS 512 // (NHID*NFEAT)/256

#if __has_builtin(__builtin_amdgcn_cvt_pk_fp8_f32) && __has_builtin(__builtin_amdgcn_cvt_pk_f32_fp8)
#define SUP_FP8 1
#else
#define SUP_FP8 0
#endif

typedef short bf16x8 __attribute__((ext_vector_type(8)));
typedef float f32x4 __attribute__((ext_vector_type(4)));
typedef float f32x2 __attribute__((ext_vector_type(2)));
typedef unsigned long long u64;

__device__ __forceinline__ unsigned short f2bf(float f) {
    unsigned int u = __builtin_bit_cast(unsigned int, f);
    u += 0x7fffu + ((u >> 16) & 1u);           // round-to-nearest-even
    return (unsigned short)(u >> 16);
}
__device__ __forceinline__ float bflo(unsigned int u) { return __builtin_bit_cast(float, u << 16); }
__device__ __forceinline__ float bfhi(unsigned int u) { return __builtin_bit_cast(float, u & 0xffff0000u); }
__device__ __forceinline__ unsigned int ecol_of(u64 ev) { return (unsigned int)(ev & 0xffffffffu); }
__device__ __forceinline__ float eval_of(u64 ev) { return __builtin_bit_cast(float, (unsigned int)(ev >> 32)); }

// ---------------- CSR pass A + weight transpose (merged) ----------------
__global__ __launch_bounds__(256) void k_histA_wt(const int* __restrict__ erow, int* __restrict__ hist,
                                                  const float* __restrict__ W1, const float* __restrict__ W2,
                                                  unsigned short* __restrict__ W1T, unsigned short* __restrict__ W2T) {
    __shared__ int lh[NB1];
    const int t = threadIdx.x, blk = blockIdx.x;
    if (blk < NBLK) {
        lh[t] = 0;
        __syncthreads();
        const int base = blk * CHUNK;
        for (int i = t; i < CHUNK; i += 256)
            atomicAdd(&lh[erow[base + i] / RPB1], 1);
        __syncthreads();
        hist[blk * NB1 + t] = lh[t];
    } else {
        int i = (blk - NBLK) * 256 + t;   // 0 .. NHID*NFEAT-1
        int nn = i >> 9, k = i & 511;
        W1T[i] = f2bf(W1[k * NHID + nn]);
        if (i < 64 * NHID) {
            int n2 = i >> 8, k2 = i & 255;
            W2T[i] = (n2 < NCLASS) ? f2bf(W2[k2 * NCLASS + n2]) : (unsigned short)0;
        }
    }
}

__global__ __launch_bounds__(256) void k_scanB(const int* __restrict__ hist,
                                               int* __restrict__ offs, int* __restrict__ bucketptr) {
    __shared__ int sd[256];
    const int b = threadIdx.x;
    int run = 0;
#pragma unroll 8
    for (int blk = 0; blk < NBLK; ++blk) {
        int v = hist[blk * NB1 + b];
        offs[blk * NB1 + b] = run;
        run += v;
    }
    sd[b] = run;
    __syncthreads();
    for (int off = 1; off < 256; off <<= 1) {
        int x = (b >= off) ? sd[b - off] : 0;
        __syncthreads();
        sd[b] += x;
        __syncthreads();
    }
    bucketptr[b] = sd[b] - run;
    if (b == 255) bucketptr[NB1] = sd[255];
}

// Pass C: in-LDS counting sort (hist reused), linear nt write-out
__global__ __launch_bounds__(256) void k_scatC(const int* __restrict__ erow, const int* __restrict__ ecol,
                                               const float* __restrict__ eval_,
                                               const int* __restrict__ hist,
                                               const int* __restrict__ offs, const int* __restrict__ bucketptr,
                                               u64* __restrict__ tmp) {
    __shared__ u64 srec[CHUNK];            // 100 KB
    __shared__ unsigned char sbkt[CHUNK];  // 12.5 KB
    __shared__ int lscan[NB1];
    __shared__ int lcur[NB1];
    __shared__ int lsegbase[NB1];
    __shared__ int sd[256];
    const int t = threadIdx.x, blk = blockIdx.x;
    const int base = blk * CHUNK;
    lsegbase[t] = bucketptr[t] + offs[blk * NB1 + t];
    int v = hist[blk * NB1 + t];
    sd[t] = v;
    __syncthreads();
    for (int off = 1; off < 256; off <<= 1) {
        int x = (t >= off) ? sd[t - off] : 0;
        __syncthreads();
        sd[t] += x;
        __syncthreads();
    }
    lscan[t] = sd[t] - v;
    lcur[t] = sd[t] - v;
    __syncthreads();
    for (int i = t; i < CHUNK; i += 256) {
        int r = erow[base + i];
        int c = ecol[base + i];
        unsigned int vb = __builtin_bit_cast(unsigned int, eval_[base + i]);
        int b = r / RPB1;
        int rl = r - b * RPB1;
        int pos = atomicAdd(&lcur[b], 1);
        srec[pos] = (u64)((unsigned int)c | ((unsigned int)rl << 17)) | ((u64)vb << 32);
        sbkt[pos] = (unsigned char)b;
    }
    __syncthreads();
    for (int i = t; i < CHUNK; i += 256) {
        int b = sbkt[i];
        __builtin_nontemporal_store(srec[i], &tmp[lsegbase[b] + (i - lscan[b])]);
    }
}

// Pass D: per-bucket fine sort; records cached in LDS (single nt read of tmp)
__global__ __launch_bounds__(512) void k_sortD(const int* __restrict__ bucketptr, const u64* __restrict__ tmp,
                                               u64* __restrict__ pedge, int* __restrict__ rowptr) {
    __shared__ u64 srec[SCAP];             // 106.5 KB
    __shared__ int lcnt[512];
    __shared__ int sc[512];
    __shared__ int lcur[512];
    const int b = blockIdx.x, t = threadIdx.x;
    const int beg = bucketptr[b], end = bucketptr[b + 1];
    const int n = end - beg;
    lcnt[t] = 0;
    __syncthreads();
    for (int i = t; i < n; i += 512) {
        u64 rec = __builtin_nontemporal_load(&tmp[beg + i]);
        if (i < SCAP) srec[i] = rec;
        atomicAdd(&lcnt[(int)((rec >> 17) & 0x1ff)], 1);
    }
    __syncthreads();
    sc[t] = lcnt[t];
    __syncthreads();
    for (int off = 1; off < 512; off <<= 1) {
        int x = (t >= off) ? sc[t - off] : 0;
        __syncthreads();
        sc[t] += x;
        __syncthreads();
    }
    int excl = sc[t] - lcnt[t];
    lcur[t] = excl;
    if (t < RPB1) {
        int row = b * RPB1 + t;
        if (row < N_NODES) rowptr[row] = beg + excl;
    }
    if (b == NB1 - 1 && t == 0) rowptr[N_NODES] = N_EDGES;
    __syncthreads();
    for (int i = t; i < n; i += 512) {
        u64 rec = (i < SCAP) ? srec[i] : __builtin_nontemporal_load(&tmp[beg + i]);
        int rl = (int)((rec >> 17) & 0x1ff);
        int pos = atomicAdd(&lcur[rl], 1);
        pedge[beg + pos] = rec & 0xFFFFFFFF0001FFFFull;
    }
}

// ---------------- GEMM1: support[row][256] = bf16(x) @ bf16(W1), stored fp8 ----------------
// register prefetch + LDS double-buffer, ONE barrier per K-step
__global__ __launch_bounds__(512) void k_gemm1(const float* __restrict__ X,
                                               const unsigned short* __restrict__ W1T,
                                               unsigned char* __restrict__ support8) {
    __shared__ unsigned short As[2][128 * LDP];
    __shared__ unsigned short Bs[2][256 * LDP];
    const int t = threadIdx.x;
    const int lane = t & 63;
    const int w = t >> 6;
    const int wm = w >> 2, wn = w & 3;
    const int l15 = lane & 15, l4 = lane >> 4;
    const int bm = blockIdx.x;

    f32x4 acc[4][4];
#pragma unroll
    for (int m = 0; m < 4; ++m)
#pragma unroll
        for (int n = 0; n < 4; ++n) acc[m][n] = (f32x4){0.f, 0.f, 0.f, 0.f};

    const int arow = t >> 2, aq = t & 3;
    const long growA = (long)bm * 128 + arow;
    const bool avalid = growA < N_NODES;
    const float* xsrc = X + growA * NFEAT + aq * 8;
    const int brow = t >> 1, bhalf = t & 1;
    const unsigned short* bsrc = W1T + (long)brow * NFEAT + bhalf * 16;
    const int adoff = arow * LDP + aq * 8;
    const int bdoff = brow * LDP + bhalf * 16;

    float4 a0r, a1r;
    uint4 b0r, b1r;
    if (avalid) {
        a0r = *(const float4*)(xsrc + 0);
        a1r = *(const float4*)(xsrc + 4);
    } else {
        a0r = make_float4(0.f, 0.f, 0.f, 0.f);
        a1r = make_float4(0.f, 0.f, 0.f, 0.f);
    }
    b0r = *(const uint4*)(bsrc + 0);
    b1r = *(const uint4*)(bsrc + 8);
    {
        union { uint4 q; unsigned short us[8]; } u;
        const float* af = (const float*)&a0r;
#pragma unroll
        for (int j = 0; j < 4; ++j) u.us[j] = f2bf(af[j]);
        const float* af1 = (const float*)&a1r;
#pragma unroll
        for (int j = 0; j < 4; ++j) u.us[4 + j] = f2bf(af1[j]);
        *(uint4*)&As[0][adoff] = u.q;
        *(uint4*)&Bs[0][bdoff] = b0r;
        *(uint4*)&Bs[0][bdoff + 8] = b1r;
    }
    __syncthreads();

    for (int ki = 0; ki < 16; ++ki) {
        const int cur = ki & 1;
        if (ki < 15) {
            int kt = (ki + 1) * 32;
            if (avalid) {
                a0r = *(const float4*)(xsrc + kt);
                a1r = *(const float4*)(xsrc + kt + 4);
            }
            b0r = *(const uint4*)(bsrc + kt);
            b1r = *(const uint4*)(bsrc + kt + 8);
        }

        bf16x8 afr[4], bfr[4];
#pragma unroll
        for (int m = 0; m < 4; ++m)
            afr[m] = *(const bf16x8*)&As[cur][(wm * 64 + m * 16 + l15) * LDP + l4 * 8];
#pragma unroll
        for (int n = 0; n < 4; ++n)
            bfr[n] = *(const bf16x8*)&Bs[cur][(wn * 64 + n * 16 + l15) * LDP + l4 * 8];
#pragma unroll
        for (int m = 0; m < 4; ++m)
#pragma unroll
            for (int n = 0; n < 4; ++n)
                acc[m][n] = __builtin_amdgcn_mfma_f32_16x16x32_bf16(bfr[n], afr[m], acc[m][n], 0, 0, 0);

        if (ki < 15) {
            union { uint4 q; unsigned short us[8]; } u;
            const float* af = (const float*)&a0r;
#pragma unroll
            for (int j = 0; j < 4; ++j) u.us[j] = avalid ? f2bf(af[j]) : (unsigned short)0;
            const float* af1 = (const float*)&a1r;
#pragma unroll
            for (int j = 0; j < 4; ++j) u.us[4 + j] = avalid ? f2bf(af1[j]) : (unsigned short)0;
            *(uint4*)&As[cur ^ 1][adoff] = u.q;
            *(uint4*)&Bs[cur ^ 1][bdoff] = b0r;
            *(uint4*)&Bs[cur ^ 1][bdoff + 8] = b1r;
        }
        __syncthreads();
    }

#pragma unroll
    for (int m = 0; m < 4; ++m) {
        long row = (long)bm * 128 + wm * 64 + m * 16 + l15;
        if (row < N_NODES) {
#pragma unroll
            for (int n = 0; n < 4; ++n) {
                int colb = wn * 64 + n * 16 + l4 * 4;
#if SUP_FP8
                int wv = 0;
                wv = __builtin_amdgcn_cvt_pk_fp8_f32(acc[m][n][0], acc[m][n][1], wv, false);
                wv = __builtin_amdgcn_cvt_pk_fp8_f32(acc[m][n][2], acc[m][n][3], wv, true);
                *(unsigned int*)&support8[(size_t)row * NHID + colb] = (unsigned int)wv;
#else
                ushort4 o;
                o.x = f2bf(acc[m][n][0]);
                o.y = f2bf(acc[m][n][1]);
                o.z = f2bf(acc[m][n][2]);
                o.w = f2bf(acc[m][n][3]);
                *(ushort4*)&support8[(size_t)row * NHID * 2 + colb * 2] = o;
#endif
            }
        }
    }
}

// ---------------- SpMM1 + bias + ReLU -> h (bf16). one wave per row, 8-way MLP, fp8 gather ----------------
// (R13 version — reverted from R14's column-sliced variant, which regressed 145->252 us)
__global__ __launch_bounds__(256) void k_spmm1(const int* __restrict__ rowptr,
                                               const u64* __restrict__ pedge,
                                               const unsigned char* __restrict__ support8,
                                               const float* __restrict__ b1,
                                               unsigned short* __restrict__ h) {
    int wrow = (blockIdx.x * 256 + threadIdx.x) >> 6;
    int lane = threadIdx.x & 63;
    if (wrow >= N_NODES) return;
    int beg = rowptr[wrow], end = rowptr[wrow + 1];
    float a0 = 0.f, a1 = 0.f, a2 = 0.f, a3 = 0.f;
    const int c4 = lane * 4;
    int e = beg;
#if SUP_FP8
    for (; e + 8 <= end; e += 8) {
        u64 ev[8];
#pragma unroll
        for (int j = 0; j < 8; ++j) ev[j] = __builtin_nontemporal_load(&pedge[e + j]);
        unsigned int g[8];
#pragma unroll
        for (int j = 0; j < 8; ++j)
            g[j] = *(const unsigned int*)&support8[(size_t)ecol_of(ev[j]) * NHID + c4];
#pragma unroll
        for (int j = 0; j < 8; ++j) {
            float v = eval_of(ev[j]);
            f32x2 lo = __builtin_amdgcn_cvt_pk_f32_fp8(g[j], false);
            f32x2 hi = __builtin_amdgcn_cvt_pk_f32_fp8(g[j], true);
            a0 = fmaf(v, lo[0], a0); a1 = fmaf(v, lo[1], a1);
            a2 = fmaf(v, hi[0], a2); a3 = fmaf(v, hi[1], a3);
        }
    }
    for (; e < end; ++e) {
        u64 ev = __builtin_nontemporal_load(&pedge[e]);
        float v = eval_of(ev);
        unsigned int g = *(const unsigned int*)&support8[(size_t)ecol_of(ev) * NHID + c4];
        f32x2 lo = __builtin_amdgcn_cvt_pk_f32_fp8(g, false);
        f32x2 hi = __builtin_amdgcn_cvt_pk_f32_fp8(g, true);
        a0 = fmaf(v, lo[0], a0); a1 = fmaf(v, lo[1], a1);
        a2 = fmaf(v, hi[0], a2); a3 = fmaf(v, hi[1], a3);
    }
#else
    for (; e + 8 <= end; e += 8) {
        u64 ev[8];
#pragma unroll
        for (int j = 0; j < 8; ++j) ev[j] = __builtin_nontemporal_load(&pedge[e + j]);
        uint2 g[8];
#pragma unroll
        for (int j = 0; j < 8; ++j)
            g[j] = *(const uint2*)&support8[((size_t)ecol_of(ev[j]) * NHID + c4) * 2];
#pragma unroll
        for (int j = 0; j < 8; ++j) {
            float v = eval_of(ev[j]);
            a0 = fmaf(v, bflo(g[j].x), a0); a1 = fmaf(v, bfhi(g[j].x), a1);
            a2 = fmaf(v, bflo(g[j].y), a2); a3 = fmaf(v, bfhi(g[j].y), a3);
        }
    }
    for (; e < end; ++e) {
        u64 ev = __builtin_nontemporal_load(&pedge[e]);
        float v = eval_of(ev);
        uint2 g = *(const uint2*)&support8[((size_t)ecol_of(ev) * NHID + c4) * 2];
        a0 = fmaf(v, bflo(g.x), a0); a1 = fmaf(v, bfhi(g.x), a1);
        a2 = fmaf(v, bflo(g.y), a2); a3 = fmaf(v, bfhi(g.y), a3);
    }
#endif
    float4 bb = *(const float4*)&b1[c4];
    a0 = fmaxf(a0 + bb.x, 0.f);
    a1 = fmaxf(a1 + bb.y, 0.f);
    a2 = fmaxf(a2 + bb.z, 0.f);
    a3 = fmaxf(a3 + bb.w, 0.f);
    ushort4 o;
    o.x = f2bf(a0); o.y = f2bf(a1); o.z = f2bf(a2); o.w = f2bf(a3);
    *(ushort4*)&h[(size_t)wrow * NHID + c4] = o;
}

// ---------------- GEMM2: logits8[row][40] (fp8, 4 MB table -> L2-resident) = h @ W2 ----------------
__global__ __launch_bounds__(256) void k_gemm2(const unsigned short* __restrict__ H,
                                               const unsigned short* __restrict__ W2T,
                                               unsigned char* __restrict__ logits8) {
    __shared__ unsigned short As[128 * LDP];
    __shared__ unsigned short Bs[64 * LDP];
    const int t = threadIdx.x;
    const int lane = t & 63;
    const int w = t >> 6;
    const int wm = w >> 1, wn = w & 1;
    const int l15 = lane & 15, l4 = lane >> 4;
    const int bm = blockIdx.x;

    f32x4 acc[4][2];
#pragma unroll
    for (int m = 0; m < 4; ++m)
#pragma unroll
        for (int n = 0; n < 2; ++n) acc[m][n] = (f32x4){0.f, 0.f, 0.f, 0.f};

    const int srow = t >> 1, shalf = t & 1;
    const long grow = (long)bm * 128 + srow;
    const bool avalid = grow < N_NODES;
    const unsigned short* asrc = H + grow * NHID + shalf * 16;
    const int bn2 = t >> 2, bq = t & 3;
    const unsigned short* bsrc = W2T + bn2 * NHID + bq * 8;

    for (int kt = 0; kt < NHID; kt += 32) {
        uint4 a0, a1;
        if (avalid) {
            a0 = *(const uint4*)(asrc + kt);
            a1 = *(const uint4*)(asrc + kt + 8);
        } else {
            a0 = make_uint4(0, 0, 0, 0);
            a1 = make_uint4(0, 0, 0, 0);
        }
        uint4 bv = *(const uint4*)(bsrc + kt);
        *(uint4*)&As[srow * LDP + shalf * 16] = a0;
        *(uint4*)&As[srow * LDP + shalf * 16 + 8] = a1;
        *(uint4*)&Bs[bn2 * LDP + bq * 8] = bv;
        __syncthreads();

        bf16x8 afr[4], bfr[2];
#pragma unroll
        for (int m = 0; m < 4; ++m)
            afr[m] = *(const bf16x8*)&As[(wm * 64 + m * 16 + l15) * LDP + l4 * 8];
#pragma unroll
        for (int n = 0; n < 2; ++n)
            bfr[n] = *(const bf16x8*)&Bs[(wn * 32 + n * 16 + l15) * LDP + l4 * 8];
#pragma unroll
        for (int m = 0; m < 4; ++m)
#pragma unroll
            for (int n = 0; n < 2; ++n)
                acc[m][n] = __builtin_amdgcn_mfma_f32_16x16x32_bf16(bfr[n], afr[m], acc[m][n], 0, 0, 0);
        __syncthreads();
    }
#pragma unroll
    for (int m = 0; m < 4; ++m) {
        long row = (long)bm * 128 + wm * 64 + m * 16 + l15;
        if (row < N_NODES) {
#pragma unroll
            for (int n = 0; n < 2; ++n) {
                int colb = wn * 32 + n * 16 + l4 * 4;
                if (colb < NCLASS) {
#if SUP_FP8
                    int wv = 0;
                    wv = __builtin_amdgcn_cvt_pk_fp8_f32(acc[m][n][0], acc[m][n][1], wv, false);
                    wv = __builtin_amdgcn_cvt_pk_fp8_f32(acc[m][n][2], acc[m][n][3], wv, true);
                    *(unsigned int*)&logits8[(size_t)row * NCLASS + colb] = (unsigned int)wv;
#else
                    ushort4 o;
                    o.x = f2bf(acc[m][n][0]);
                    o.y = f2bf(acc[m][n][1]);
                    o.z = f2bf(acc[m][n][2]);
                    o.w = f2bf(acc[m][n][3]);
                    *(ushort4*)&logits8[((size_t)row * NCLASS + colb) * 2] = o;
#endif
                }
            }
        }
    }
}

// ---------------- SpMM2 + bias + log_softmax -> out (fp32) ----------------
// lane = eg*8+cl: 8 edge-groups x 8 col-lanes (cl<5 active, 8 fp8 cols each).
__global__ __launch_bounds__(256) void k_spmm2(const int* __restrict__ rowptr,
                                               const u64* __restrict__ pedge,
                                               const unsigned char* __restrict__ logits8,
                                               const float* __restrict__ b2, float* __restrict__ out) {
    int wrow = (blockIdx.x * 256 + threadIdx.x) >> 6;
    int lane = threadIdx.x & 63;
    if (wrow >= N_NODES) return;
    int beg = rowptr[wrow], end = rowptr[wrow + 1];
    const int eg = lane >> 3;      // 0..7 edge subgroup
    const int cl = lane & 7;       // 0..7, active if <5
    const bool colact = cl < 5;
    const int cb = colact ? cl * 8 : 0;   // column base (8 cols per lane)
    float acc[8];
#pragma unroll
    for (int j = 0; j < 8; ++j) acc[j] = 0.f;
#if SUP_FP8
    for (int e = beg + eg; e < end; e += 8) {
        u64 ev = __builtin_nontemporal_load(&pedge[e]);
        float v = eval_of(ev);
        uint2 g = *(const uint2*)&logits8[(size_t)ecol_of(ev) * NCLASS + cb];
        f32x2 p0 = __builtin_amdgcn_cvt_pk_f32_fp8(g.x, false);
        f32x2 p1 = __builtin_amdgcn_cvt_pk_f32_fp8(g.x, true);
        f32x2 p2 = __builtin_amdgcn_cvt_pk_f32_fp8(g.y, false);
        f32x2 p3 = __builtin_amdgcn_cvt_pk_f32_fp8(g.y, true);
        acc[0] = fmaf(v, p0[0], acc[0]); acc[1] = fmaf(v, p0[1], acc[1]);
        acc[2] = fmaf(v, p1[0], acc[2]); acc[3] = fmaf(v, p1[1], acc[3]);
        acc[4] = fmaf(v, p2[0], acc[4]); acc[5] = fmaf(v, p2[1], acc[5]);
        acc[6] = fmaf(v, p3[0], acc[6]); acc[7] = fmaf(v, p3[1], acc[7]);
    }
#else
    for (int e = beg + eg; e < end; e += 8) {
        u64 ev = __builtin_nontemporal_load(&pedge[e]);
        float v = eval_of(ev);
        uint4 g = *(const uint4*)&logits8[((size_t)ecol_of(ev) * NCLASS + cb) * 2];
        acc[0] = fmaf(v, bflo(g.x), acc[0]); acc[1] = fmaf(v, bfhi(g.x), acc[1]);
        acc[2] = fmaf(v, bflo(g.y), acc[2]); acc[3] = fmaf(v, bfhi(g.y), acc[3]);
        acc[4] = fmaf(v, bflo(g.z), acc[4]); acc[5] = fmaf(v, bfhi(g.z), acc[5]);
        acc[6] = fmaf(v, bflo(g.w), acc[6]); acc[7] = fmaf(v, bfhi(g.w), acc[7]);
    }
#endif
#pragma unroll
    for (int off = 8; off < 64; off <<= 1)
#pragma unroll
        for (int j = 0; j < 8; ++j)
            acc[j] += __shfl_xor(acc[j], off, 64);
    if (colact) {
        float4 bb0 = *(const float4*)&b2[cb];
        float4 bb1 = *(const float4*)&b2[cb + 4];
        acc[0] += bb0.x; acc[1] += bb0.y; acc[2] += bb0.z; acc[3] += bb0.w;
        acc[4] += bb1.x; acc[5] += bb1.y; acc[6] += bb1.z; acc[7] += bb1.w;
    }
    float mv = -INFINITY;
    if (colact) {
#pragma unroll
        for (int j = 0; j < 8; ++j) mv = fmaxf(mv, acc[j]);
    }
#pragma unroll
    for (int off = 1; off < 8; off <<= 1) mv = fmaxf(mv, __shfl_xor(mv, off, 64));
    float s = 0.f;
    if (colact) {
#pragma unroll
        for (int j = 0; j < 8; ++j) s += __expf(acc[j] - mv);
    }
#pragma unroll
    for (int off = 1; off < 8; off <<= 1) s += __shfl_xor(s, off, 64);
    if (colact && eg == 0) {
        float ls = __logf(s);
        float4 o0, o1;
        o0.x = acc[0] - mv - ls; o0.y = acc[1] - mv - ls;
        o0.z = acc[2] - mv - ls; o0.w = acc[3] - mv - ls;
        o1.x = acc[4] - mv - ls; o1.y = acc[5] - mv - ls;
        o1.z = acc[6] - mv - ls; o1.w = acc[7] - mv - ls;
        *(float4*)&out[(size_t)wrow * NCLASS + cb] = o0;
        *(float4*)&out[(size_t)wrow * NCLASS + cb + 4] = o1;
    }
}

extern "C" void kernel_launch(void* const* d_in, const int* in_sizes, int n_in,
                              void* d_out, int out_size, void* d_ws, size_t ws_size,
                              hipStream_t stream) {
    const float* x    = (const float*)d_in[0];
    const int*   erow = (const int*)d_in[1];
    const int*   ecol = (const int*)d_in[2];
    const float* eval_ = (const float*)d_in[3];
    const float* W1   = (const float*)d_in[4];
    const float* b1   = (const float*)d_in[5];
    const float* W2   = (const float*)d_in[6];
    const float* b2   = (const float*)d_in[7];
    float* out = (float*)d_out;

    char* p = (char*)d_ws;
    auto alloc = [&](size_t b) { char* r = p; p += (b + 255) & ~(size_t)255; return r; };
    int* hist              = (int*)alloc((size_t)NBLK * NB1 * 4);
    int* offs              = (int*)alloc((size_t)NBLK * NB1 * 4);
    int* bucketptr         = (int*)alloc((size_t)(NB1 + 1) * 4);
    int* rowptr            = (int*)alloc((size_t)(N_NODES + 1) * 4);
    u64* tmp               = (u64*)alloc((size_t)N_EDGES * 8);
    u64* pedge             = (u64*)alloc((size_t)N_EDGES * 8);
    unsigned short* W1T    = (unsigned short*)alloc((size_t)NHID * NFEAT * 2);
    unsigned short* W2T    = (unsigned short*)alloc((size_t)64 * NHID * 2);
    unsigned char* support8= (unsigned char*)alloc((size_t)N_NODES * NHID * 2); // 2B reserved (bf16 fallback)
    unsigned short* h      = (unsigned short*)alloc((size_t)N_NODES * NHID * 2);
    unsigned char* logits8 = (unsigned char*)alloc((size_t)N_NODES * NCLASS * 2); // 2B reserved (bf16 fallback)

    k_histA_wt<<<NBLK + WTBLKS, 256, 0, stream>>>(erow, hist, W1, W2, W1T, W2T);
    k_scanB<<<1, 256, 0, stream>>>(hist, offs, bucketptr);
    k_scatC<<<NBLK, 256, 0, stream>>>(erow, ecol, eval_, hist, offs, bucketptr, tmp);
    k_sortD<<<NB1, 512, 0, stream>>>(bucketptr, tmp, pedge, rowptr);
    k_gemm1<<<(N_NODES + 127) / 128, 512, 0, stream>>>(x, W1T, support8);
    k_spmm1<<<(N_NODES + 3) / 4, 256, 0, stream>>>(rowptr, pedge, support8, b1, h);
    k_gemm2<<<(N_NODES + 127) / 128, 256, 0, stream>>>(h, W2T, logits8);
    k_spmm2<<<(N_NODES + 3) / 4, 256, 0, stream>>>(rowptr, pedge, logits8, b2, out);
}